// Round 4
// baseline (362.123 us; speedup 1.0000x reference)
//
#include <hip/hip_runtime.h>
#include <hip/hip_fp16.h>
#include <cmath>

#define EPS 1e-5f
#define TAU 0.15f
#define RP  8

// Problem constants (fixed instance)
#define Bn 16
#define Dn 256
#define Tn 4096
#define Kn 2048

typedef unsigned short ushort_t;
typedef __attribute__((ext_vector_type(8))) _Float16 f16x8;
typedef __attribute__((ext_vector_type(4))) float f32x4;

__device__ __forceinline__ unsigned short f2h(float v) {
    return __half_as_ushort(__float2half_rn(v));
}

#define GLOAD_LDS16(gp, lp) __builtin_amdgcn_global_load_lds( \
    (const __attribute__((address_space(1))) unsigned int*)(gp), \
    (__attribute__((address_space(3))) unsigned int*)(lp), 16, 0, 0)

// ---------------------------------------------------------------------------
// Kernel 1: prep — emb = es/max(usage,eps); e16 fp16 plane; bias = 0.5|e|^2;
// embT4 transpose. (unchanged)
// ---------------------------------------------------------------------------
__global__ __launch_bounds__(256) void prep_kernel(
    const float* __restrict__ es, const float* __restrict__ usage,
    float* __restrict__ emb, ushort_t* __restrict__ e16,
    float* __restrict__ bias, float4* __restrict__ embT4,
    int* __restrict__ counter)
{
    __shared__ float sh[256];
    __shared__ float wsum[4];
    const int k = blockIdx.x;
    const int d = threadIdx.x;
    const float inv = 1.0f / fmaxf(usage[k], EPS);
    const float v = es[(size_t)k * Dn + d] * inv;
    emb[(size_t)k * Dn + d] = v;
    e16[(size_t)k * Dn + d] = f2h(fminf(fmaxf(v, -65504.f), 65504.f));
    sh[d] = v;
    float sq = v * v;
    #pragma unroll
    for (int off = 32; off > 0; off >>= 1) sq += __shfl_down(sq, off, 64);
    const int lane = d & 63, wv = d >> 6;
    if (lane == 0) wsum[wv] = sq;
    __syncthreads();
    if (d < 64)
        embT4[(size_t)d * Kn + k] = make_float4(sh[4*d], sh[4*d+1], sh[4*d+2], sh[4*d+3]);
    if (d == 0) {
        bias[k] = 0.5f * (wsum[0] + wsum[1] + wsum[2] + wsum[3]);
        if (k == 0) *counter = 0;
    }
}

// ---------------------------------------------------------------------------
// Kernel 2: xsplit — x[b][d][t] fp32 -> xh[b][t][d] fp16. (unchanged)
// ---------------------------------------------------------------------------
__global__ __launch_bounds__(256) void xsplit_kernel(
    const float* __restrict__ x, ushort_t* __restrict__ xh)
{
    __shared__ float tile[32 * 65];
    const int t0 = blockIdx.x * 64;
    const int d0 = blockIdx.y * 32;
    const int b  = blockIdx.z;
    const int tid = threadIdx.x;

    {
        const int dl = tid >> 3, tq = tid & 7;
        const float* src = x + ((size_t)(b * Dn + d0 + dl)) * Tn + t0 + tq * 8;
        const float4 a = *(const float4*)(src);
        const float4 c = *(const float4*)(src + 4);
        float* row = &tile[dl * 65 + tq * 8];
        row[0] = a.x; row[1] = a.y; row[2] = a.z; row[3] = a.w;
        row[4] = c.x; row[5] = c.y; row[6] = c.z; row[7] = c.w;
    }
    __syncthreads();
    {
        const int t_l = tid >> 2, dq = tid & 3;
        unsigned wh[4];
        #pragma unroll
        for (int i = 0; i < 4; ++i) {
            const float a = tile[(dq * 8 + 2 * i) * 65 + t_l];
            const float g = tile[(dq * 8 + 2 * i + 1) * 65 + t_l];
            wh[i] = (unsigned)f2h(a) | ((unsigned)f2h(g) << 16);
        }
        const size_t o = ((size_t)(b * Tn + t0 + t_l)) * Dn + d0 + dq * 8;
        *(uint4*)(xh + o) = make_uint4(wh[0], wh[1], wh[2], wh[3]);
    }
}

// ---------------------------------------------------------------------------
// Kernel 3 (RING-PIPELINED): 256t tile/block, full K=2048/block, A in regs.
// Grid = 256 (1/CU), 8 waves x 32t.  B streams through a 4-slot x 32 KB LDS
// ring, staged 3 phases ahead (counted vmcnt, ONE barrier per phase: the
// WAR on slot (p+3)&3 = (p-1)&3 is guaranteed by the barrier itself, since
// every wave finished reading that slot in phase p-1).  Within a phase the
// 32 ds_read_b128 are ping-pong pipelined (bfA/bfB, lgkmcnt(8)) so LDS reads
// of group ks+1 overlap MFMAs of group ks.  setprio brackets MFMA only.
//
// vmcnt ledger (4 loads per STAGE_B, per thread):
//   prologue: bias(1) + A-h0(8) + A-h1(8) -> 17; vmcnt(8) [bias+A-h0],
//     read af0; vmcnt(0) [A-h1]; lgkm0; barrier; read af1; lgkm0; barrier;
//     stage phases 0,1,2 -> 12 outstanding.
//   phase p (p=2kc+h): vmcnt(8) [slot p ready; steady 12 out], barrier,
//     stage phase p+3 (if p+3<=31), compute slot p&3.
//   tails: p=30 vmcnt(4), p=31 vmcnt(0).
// ---------------------------------------------------------------------------
#define BARRIER_PIN()                                                         \
    __builtin_amdgcn_s_barrier();                                             \
    __builtin_amdgcn_sched_barrier(0)

#define LGKM8()                                                               \
    asm volatile("s_waitcnt lgkmcnt(8)" ::: "memory");                        \
    __builtin_amdgcn_sched_barrier(0)

#define LGKM0()                                                               \
    asm volatile("s_waitcnt lgkmcnt(0)" ::: "memory");                        \
    __builtin_amdgcn_sched_barrier(0)

// stage 32 KB B-chunk (128 k x 128 d half) with inverse-swizzled source
#define STAGE_B(dst, kcc, hh)                                                 \
    {                                                                         \
        _Pragma("unroll")                                                     \
        for (int r = 0; r < 4; ++r) {                                         \
            const int c   = r * 512 + tid;                                    \
            const int row = c >> 4;                                           \
            const int col = (((c & 15) ^ (row & 15)) << 3);                   \
            GLOAD_LDS16(e16 + ((size_t)((kcc) * 128 + row)) * Dn + (hh) * 128 + col, \
                        (dst) + ((r * 512 + (wid << 6)) << 3));               \
        }                                                                     \
    }

// stage 64 KB A-half (256 t x 128 d) with inverse-swizzled source
#define STAGE_A(dst, hh)                                                      \
    {                                                                         \
        _Pragma("unroll")                                                     \
        for (int r = 0; r < 8; ++r) {                                         \
            const int c   = r * 512 + tid;                                    \
            const int row = c >> 4;                                           \
            const int col = (((c & 15) ^ (row & 15)) << 3);                   \
            GLOAD_LDS16(xh + (bTt0 + row) * Dn + (hh) * 128 + col,            \
                        (dst) + ((r * 512 + (wid << 6)) << 3));               \
        }                                                                     \
    }

// read this wave's A fragments for one d-half from an LDS region
#define READ_AF(afArr, buf)                                                   \
    {                                                                         \
        _Pragma("unroll")                                                     \
        for (int ks = 0; ks < 4; ++ks)                                        \
            _Pragma("unroll")                                                 \
            for (int i = 0; i < 2; ++i)                                       \
                afArr[ks * 2 + i] = *(const f16x8*)(                          \
                    &(buf)[((wm << 5) + (i << 4) + l15) * 128 +               \
                           ((((ks << 2) | quad) ^ l15) << 3)]);               \
    }

// read one ks-group's 8 B fragments
#define READ_BF(dst, bb, ks)                                                  \
    {                                                                         \
        _Pragma("unroll")                                                     \
        for (int j = 0; j < 8; ++j)                                           \
            dst[j] = *(const f16x8*)((bb) + ((j << 4) + l15) * 128 +          \
                                     ((((ks << 2) | quad) ^ l15) << 3));      \
    }

// one ks-group of 16 MFMAs (af pair 2ks,2ks+1 x 8 j), setprio-bracketed
#define MFMA_GRP(afArr, ks, bfArr)                                            \
    {                                                                         \
        __builtin_amdgcn_s_setprio(1);                                        \
        _Pragma("unroll")                                                     \
        for (int j = 0; j < 8; ++j) {                                         \
            acc[0][j] = __builtin_amdgcn_mfma_f32_16x16x32_f16(               \
                afArr[(ks) * 2], bfArr[j], acc[0][j], 0, 0, 0);               \
            acc[1][j] = __builtin_amdgcn_mfma_f32_16x16x32_f16(               \
                afArr[(ks) * 2 + 1], bfArr[j], acc[1][j], 0, 0, 0);           \
        }                                                                     \
        __builtin_amdgcn_s_setprio(0);                                        \
    }

__global__ __launch_bounds__(512, 2) void gemm_argmax(
    const ushort_t* __restrict__ xh, const ushort_t* __restrict__ e16,
    const float* __restrict__ bias_g, int* __restrict__ codes_i,
    float* __restrict__ codes_f, int* __restrict__ list,
    int* __restrict__ counter)
{
    __shared__ __align__(16) ushort_t Bring[4][128 * 128];   // 4 x 32 KB ring
    __shared__ __align__(16) float    biasLds[2048];         // 8 KB

    const int bid = blockIdx.x;          // 256 blocks: one 256-t tile each
    const int b   = bid >> 4;
    const int tt  = bid & 15;
    const int t0  = tt << 8;

    const int tid  = threadIdx.x;
    const int lane = tid & 63;
    const int wid  = tid >> 6;           // 8 waves, each owns 32 t-rows
    const int l15  = lane & 15;
    const int quad = lane >> 4;
    const int wm   = wid;                // t-block of 32 rows

    const size_t bTt0 = (size_t)b * Tn + t0;
    ushort_t* const ring = &Bring[0][0];

    // persistent A fragments: 2 halves x (4 ks x 2 i) = 16 f16x8 = 64 VGPR
    f16x8 af0[8], af1[8];
    // accumulators: 2 i x 8 j = 64 regs
    f32x4 acc[2][8];
    // top-2 state per (i,r): 24 regs
    float S1[2][4], S2[2][4];
    int   K1[2][4];
    #pragma unroll
    for (int i = 0; i < 2; ++i)
        #pragma unroll
        for (int r = 0; r < 4; ++r) { S1[i][r] = -INFINITY; S2[i][r] = -INFINITY; K1[i][r] = 0; }
    #pragma unroll
    for (int i = 0; i < 2; ++i)
        #pragma unroll
        for (int j = 0; j < 8; ++j)
            acc[i][j] = (f32x4){-INFINITY, -INFINITY, -INFINITY, -INFINITY};

    // ---- prologue ----
    GLOAD_LDS16(bias_g + (tid << 2), biasLds + (wid << 8));   // 1
    STAGE_A(ring, 0);                                         // 8 -> slots 0,1
    STAGE_A(ring + (2 << 14), 1);                             // 8 -> slots 2,3
    asm volatile("s_waitcnt vmcnt(8)" ::: "memory");          // bias + A-h0
    BARRIER_PIN();
    READ_AF(af0, ring);
    asm volatile("s_waitcnt vmcnt(0)" ::: "memory");          // A-h1 landed
    LGKM0();                                                  // af0 in regs
    BARRIER_PIN();                                            // slots 0,1 free
    READ_AF(af1, (ring + (2 << 14)));
    LGKM0();                                                  // af1 in regs
    BARRIER_PIN();                                            // slots 2,3 free
    STAGE_B(ring,             0, 0);                          // phase 0
    STAGE_B(ring + (1 << 14), 0, 1);                          // phase 1
    STAGE_B(ring + (2 << 14), 1, 0);                          // phase 2 -> 12 out

    #pragma unroll 1
    for (int kc = 0; kc < 16; ++kc) {
        ushort_t* const bb0 = ring + ((((kc << 1))     & 3) << 14);
        ushort_t* const bb1 = ring + ((((kc << 1) + 1) & 3) << 14);
        ushort_t* const st0 = ring + ((((kc << 1) + 3) & 3) << 14);
        ushort_t* const st1 = ring + ((((kc << 1) + 4) & 3) << 14);
        f16x8 bfA[8], bfB[8];

        // ---------------- phase h0 (d 0..127, slot 2kc&3) ----------------
        if (kc < 15) { asm volatile("s_waitcnt vmcnt(8)" ::: "memory"); }
        else         { asm volatile("s_waitcnt vmcnt(4)" ::: "memory"); }
        BARRIER_PIN();
        if (kc < 15) STAGE_B(st0, kc + 1, 1);     // stage phase 2kc+3
        float bj[8];
        #pragma unroll
        for (int j = 0; j < 8; ++j) bj[j] = biasLds[(kc << 7) + (j << 4) + l15];
        READ_BF(bfA, bb0, 0);
        READ_BF(bfB, bb0, 1);
        LGKM8();                                   // bj + bfA ready
        {   // group ks=0: drain prev-kc acc (top-2 insert) + C=-bias re-init
            const int kdrb = ((kc - 1) << 7) + l15;
            __builtin_amdgcn_s_setprio(1);
            #pragma unroll
            for (int j = 0; j < 8; ++j) {
                const float nb = -bj[j];
                const f32x4 cin = {nb, nb, nb, nb};
                const int kdr = kdrb + (j << 4);
                #pragma unroll
                for (int i = 0; i < 2; ++i) {
                    #pragma unroll
                    for (int r = 0; r < 4; ++r) {
                        const float s = acc[i][j][r];
                        S2[i][r] = __builtin_amdgcn_fmed3f(s, S1[i][r], S2[i][r]);
                        const bool gt = s > S1[i][r];
                        K1[i][r] = gt ? kdr : K1[i][r];
                        S1[i][r] = fmaxf(S1[i][r], s);
                    }
                    acc[i][j] = __builtin_amdgcn_mfma_f32_16x16x32_f16(
                        af0[i], bfA[j], cin, 0, 0, 0);
                }
            }
            __builtin_amdgcn_s_setprio(0);
        }
        READ_BF(bfA, bb0, 2);
        LGKM8();                                   // bfB ready
        MFMA_GRP(af0, 1, bfB);
        READ_BF(bfB, bb0, 3);
        LGKM8();                                   // bfA(grp2) ready
        MFMA_GRP(af0, 2, bfA);
        LGKM0();                                   // bfB(grp3) ready
        MFMA_GRP(af0, 3, bfB);

        // ---------------- phase h1 (d 128..255, slot (2kc+1)&3) ----------
        if (kc < 15) { asm volatile("s_waitcnt vmcnt(8)" ::: "memory"); }
        else         { asm volatile("s_waitcnt vmcnt(0)" ::: "memory"); }
        BARRIER_PIN();
        if (kc < 14) STAGE_B(st1, kc + 2, 0);     // stage phase 2kc+4
        READ_BF(bfA, bb1, 0);
        READ_BF(bfB, bb1, 1);
        LGKM8();
        MFMA_GRP(af1, 0, bfA);
        READ_BF(bfA, bb1, 2);
        LGKM8();
        MFMA_GRP(af1, 1, bfB);
        READ_BF(bfB, bb1, 3);
        LGKM8();
        MFMA_GRP(af1, 2, bfA);
        LGKM0();
        MFMA_GRP(af1, 3, bfB);
    }

    __builtin_amdgcn_sched_barrier(0);

    // ---- final drain of kc=15 acc ----
    {
        const int kfb = (15 << 7) + l15;
        #pragma unroll
        for (int j = 0; j < 8; ++j) {
            const int kf = kfb + (j << 4);
            #pragma unroll
            for (int i = 0; i < 2; ++i)
                #pragma unroll
                for (int r = 0; r < 4; ++r) {
                    const float s = acc[i][j][r];
                    S2[i][r] = __builtin_amdgcn_fmed3f(s, S1[i][r], S2[i][r]);
                    const bool gt = s > S1[i][r];
                    K1[i][r] = gt ? kf : K1[i][r];
                    S1[i][r] = fmaxf(S1[i][r], s);
                }
        }
    }

    // ---- butterfly across the 16 k-lanes (tie-break: lowest k) ----
    #pragma unroll
    for (int m = 1; m <= 8; m <<= 1) {
        #pragma unroll
        for (int i = 0; i < 2; ++i)
            #pragma unroll
            for (int r = 0; r < 4; ++r) {
                const float os1 = __shfl_xor(S1[i][r], m);
                const float os2 = __shfl_xor(S2[i][r], m);
                const int   ok1 = __shfl_xor(K1[i][r], m);
                const bool take = (os1 > S1[i][r]) || (os1 == S1[i][r] && ok1 < K1[i][r]);
                const float ns2 = take ? fmaxf(S1[i][r], os2) : fmaxf(S2[i][r], os1);
                if (take) { S1[i][r] = os1; K1[i][r] = ok1; }
                S2[i][r] = ns2;
            }
    }

    if (l15 == 0) {
        #pragma unroll
        for (int i = 0; i < 2; ++i)
            #pragma unroll
            for (int r = 0; r < 4; ++r) {
                const int row = (wm << 5) + (i << 4) + (quad << 2) + r;
                const size_t p = bTt0 + row;
                const int wk = K1[i][r];
                codes_i[p] = wk;
                codes_f[p] = (float)wk;
                if (S1[i][r] - S2[i][r] < TAU) {
                    const int idx = atomicAdd(counter, 1);
                    list[idx] = (int)p;
                }
            }
    }
}

// ---------------------------------------------------------------------------
// Kernel 5: exact fp32 rescore (unchanged)
// ---------------------------------------------------------------------------
__global__ __launch_bounds__(256) void rescue_kernel(
    const float* __restrict__ x, const float4* __restrict__ embT4,
    const float* __restrict__ bias, const int* __restrict__ list,
    const int* __restrict__ counter, int* __restrict__ codes_i,
    float* __restrict__ codes_f)
{
    __shared__ float xv[RP][256];
    __shared__ int plist[RP];
    __shared__ float rs[RP][4];
    __shared__ int   rk[RP][4];
    const int tid = threadIdx.x, lane = tid & 63, wid = tid >> 6;
    const int count = *counter;
    for (int base = blockIdx.x * RP; base < count; base += gridDim.x * RP) {
        const int npts = min(RP, count - base);
        __syncthreads();
        if (tid < npts) plist[tid] = list[base + tid];
        __syncthreads();
        for (int pi = 0; pi < npts; ++pi) {
            const int p = plist[pi];
            xv[pi][tid] = x[((size_t)((p >> 12) * Dn + tid)) * Tn + (p & 4095)];
        }
        for (int pi = npts; pi < RP; ++pi) xv[pi][tid] = 0.f;
        __syncthreads();

        float acc[8][RP];
        #pragma unroll
        for (int s = 0; s < 8; ++s)
            #pragma unroll
            for (int pi = 0; pi < RP; ++pi) acc[s][pi] = 0.f;

        for (int dc = 0; dc < 64; ++dc) {
            float4 ev[8];
            #pragma unroll
            for (int s = 0; s < 8; ++s)
                ev[s] = embT4[(size_t)dc * Kn + tid + (s << 8)];
            #pragma unroll
            for (int pi = 0; pi < RP; ++pi) {
                const float4 xw = *(const float4*)&xv[pi][dc << 2];
                #pragma unroll
                for (int s = 0; s < 8; ++s)
                    acc[s][pi] += ev[s].x * xw.x + ev[s].y * xw.y
                                + ev[s].z * xw.z + ev[s].w * xw.w;
            }
        }

        float bs[RP]; int bk[RP];
        #pragma unroll
        for (int pi = 0; pi < RP; ++pi) { bs[pi] = -INFINITY; bk[pi] = 0; }
        #pragma unroll
        for (int s = 0; s < 8; ++s) {
            const int kk = tid + (s << 8);
            const float bv = bias[kk];
            #pragma unroll
            for (int pi = 0; pi < RP; ++pi) {
                const float sc = acc[s][pi] - bv;
                if (sc > bs[pi]) { bs[pi] = sc; bk[pi] = kk; }
            }
        }
        #pragma unroll
        for (int off = 1; off < 64; off <<= 1) {
            #pragma unroll
            for (int pi = 0; pi < RP; ++pi) {
                const float os = __shfl_xor(bs[pi], off);
                const int   ok = __shfl_xor(bk[pi], off);
                if (os > bs[pi] || (os == bs[pi] && ok < bk[pi])) { bs[pi] = os; bk[pi] = ok; }
            }
        }
        if (lane == 0) {
            #pragma unroll
            for (int pi = 0; pi < RP; ++pi) { rs[pi][wid] = bs[pi]; rk[pi][wid] = bk[pi]; }
        }
        __syncthreads();
        if (tid < npts) {
            float fs = rs[tid][0]; int fk = rk[tid][0];
            #pragma unroll
            for (int w = 1; w < 4; ++w) {
                if (rs[tid][w] > fs || (rs[tid][w] == fs && rk[tid][w] < fk)) {
                    fs = rs[tid][w]; fk = rk[tid][w];
                }
            }
            const int p = plist[tid];
            codes_i[p] = fk;
            codes_f[p] = (float)fk;
        }
    }
}

// ---------------------------------------------------------------------------
// Kernel 6: decode (unchanged)
// ---------------------------------------------------------------------------
__global__ __launch_bounds__(256) void decode_kernel(
    const float* __restrict__ emb, const int* __restrict__ codes,
    float* __restrict__ out)
{
    const int b = blockIdx.y;
    const int t = blockIdx.x * 256 + threadIdx.x;
    const int c = codes[(size_t)b * Tn + t];
    const float4* e4 = (const float4*)(emb + (size_t)c * Dn);
    float* ob = out + (size_t)b * Dn * Tn + t;
    #pragma unroll 4
    for (int d4 = 0; d4 < 64; ++d4) {
        const float4 v = e4[d4];
        ob[(size_t)(d4 * 4 + 0) * Tn] = v.x;
        ob[(size_t)(d4 * 4 + 1) * Tn] = v.y;
        ob[(size_t)(d4 * 4 + 2) * Tn] = v.z;
        ob[(size_t)(d4 * 4 + 3) * Tn] = v.w;
    }
}

// ---------------------------------------------------------------------------
extern "C" void kernel_launch(void* const* d_in, const int* in_sizes, int n_in,
                              void* d_out, int out_size, void* d_ws, size_t ws_size,
                              hipStream_t stream) {
    const float* x     = (const float*)d_in[0];   // [B, D, T]
    const float* es    = (const float*)d_in[1];   // [K, D]
    const float* usage = (const float*)d_in[2];   // [K]

    // ws layout (byte offsets, 16-aligned) — ~6 MiB
    char* ws = (char*)d_ws;
    float*    emb     = (float*)(ws + 0);                // 2 MiB
    float*    bias    = (float*)(ws + 2097152);          // 8 KB
    ushort_t* e16     = (ushort_t*)(ws + 2105344);       // 1 MiB
    float4*   embT4   = (float4*)(ws + 3153920);         // 2 MiB
    int*      codes_i = (int*)(ws + 5251072);            // 256 KB
    int*      list    = (int*)(ws + 5513216);            // 256 KB
    int*      counter = (int*)(ws + 5775360);            // 4 B

    float* codes_f = (float*)d_out;                      // [B*T]
    float* decoded = (float*)d_out + (size_t)Bn * Tn;    // [B*D*T], 64 MiB

    // xh (fp16, 32 MiB) lives inside the decoded region; decode overwrites
    // at the very end, after xh is consumed.
    ushort_t* xh  = (ushort_t*)decoded;                  // 32 MiB

    prep_kernel<<<Kn, 256, 0, stream>>>(es, usage, emb, e16, bias, embT4, counter);

    dim3 gx(Tn / 64, Dn / 32, Bn);
    xsplit_kernel<<<gx, 256, 0, stream>>>(x, xh);

    // 256 blocks (one per CU), each: 256 t x full K=2048, A in registers
    gemm_argmax<<<256, 512, 0, stream>>>(xh, e16, bias, codes_i, codes_f,
                                         list, counter);

    rescue_kernel<<<1024, 256, 0, stream>>>(x, embT4, bias, list, counter, codes_i, codes_f);

    dim3 g6(Tn / 256, Bn);
    decode_kernel<<<g6, 256, 0, stream>>>(emb, codes_i, decoded);
}

// Round 5
// 305.996 us; speedup vs baseline: 1.1834x; 1.1834x over previous
//
#include <hip/hip_runtime.h>
#include <hip/hip_fp16.h>
#include <cmath>

#define EPS 1e-5f
#define TAU 0.15f
#define RP  8

// Problem constants (fixed instance)
#define Bn 16
#define Dn 256
#define Tn 4096
#define Kn 2048

typedef unsigned short ushort_t;
typedef __attribute__((ext_vector_type(8))) _Float16 f16x8;
typedef __attribute__((ext_vector_type(4))) float f32x4;

__device__ __forceinline__ unsigned short f2h(float v) {
    return __half_as_ushort(__float2half_rn(v));
}

#define GLOAD_LDS16(gp, lp) __builtin_amdgcn_global_load_lds( \
    (const __attribute__((address_space(1))) unsigned int*)(gp), \
    (__attribute__((address_space(3))) unsigned int*)(lp), 16, 0, 0)

// ---------------------------------------------------------------------------
// Kernel 1: prep — emb = es/max(usage,eps); e16 fp16 plane; bias = 0.5|e|^2;
// embT4 transpose. (unchanged)
// ---------------------------------------------------------------------------
__global__ __launch_bounds__(256) void prep_kernel(
    const float* __restrict__ es, const float* __restrict__ usage,
    float* __restrict__ emb, ushort_t* __restrict__ e16,
    float* __restrict__ bias, float4* __restrict__ embT4,
    int* __restrict__ counter)
{
    __shared__ float sh[256];
    __shared__ float wsum[4];
    const int k = blockIdx.x;
    const int d = threadIdx.x;
    const float inv = 1.0f / fmaxf(usage[k], EPS);
    const float v = es[(size_t)k * Dn + d] * inv;
    emb[(size_t)k * Dn + d] = v;
    e16[(size_t)k * Dn + d] = f2h(fminf(fmaxf(v, -65504.f), 65504.f));
    sh[d] = v;
    float sq = v * v;
    #pragma unroll
    for (int off = 32; off > 0; off >>= 1) sq += __shfl_down(sq, off, 64);
    const int lane = d & 63, wv = d >> 6;
    if (lane == 0) wsum[wv] = sq;
    __syncthreads();
    if (d < 64)
        embT4[(size_t)d * Kn + k] = make_float4(sh[4*d], sh[4*d+1], sh[4*d+2], sh[4*d+3]);
    if (d == 0) {
        bias[k] = 0.5f * (wsum[0] + wsum[1] + wsum[2] + wsum[3]);
        if (k == 0) *counter = 0;
    }
}

// ---------------------------------------------------------------------------
// Kernel 3 (round-3 schedule + A-direct-from-x): 256t tile/block, full
// K=2048/block, A in registers loaded DIRECTLY from x (fp32 -> fp16 in
// kernel; xsplit kernel and xh buffer deleted).  Grid = 256 (1/CU),
// 8 waves x 32t.  B (e16) streams through 2x32 KB double-buffered LDS
// (verified XOR-swizzle: linear gload_lds dest + inverse-swizzled source +
// swizzled ds_read), counted-vmcnt ledger identical to round 3.
//
// A-load pattern: af element e of frag (ks,i,half h) = x[b][d][t] with
// d = h*128 + ks*32 + quad*8 + e, t = t0 + wm*32 + i*16 + l15.
// For fixed (ks,i,e): 16 l15-lanes read 16 consecutive t-floats = one
// fully-used 64 B transaction.  cvt f32->f16 RTN == __float2half_rn, so
// scores are bit-identical to the old xh path.
//
// vmcnt ledger (per thread):
//   prologue: bias gload_lds (1) + 128 A scalar loads (compiler-managed);
//     vmcnt(0) [everything landed]; barrier; stage B(0,h0)(4), B(0,h1)(4)
//     -> 8 outstanding.
//   kc-phase h0: vmcnt(4) [Bs0 ready], barrier, compute, barrier,
//                restage Bs0 <- B(kc+1,h0) (4)  [kc<15]
//   kc-phase h1: vmcnt(4) (kc<15) / vmcnt(0) (kc=15), barrier, compute,
//                barrier, restage Bs1 <- B(kc+1,h1) (4) [kc<15]
// ---------------------------------------------------------------------------
#define BARRIER_PIN()                                                         \
    __builtin_amdgcn_s_barrier();                                             \
    __builtin_amdgcn_sched_barrier(0)

// stage 32 KB B-chunk (128 k x 128 d half) with inverse-swizzled source
#define STAGE_B(dst, kcc, hh)                                                 \
    {                                                                         \
        _Pragma("unroll")                                                     \
        for (int r = 0; r < 4; ++r) {                                         \
            const int c   = r * 512 + tid;                                    \
            const int row = c >> 4;                                           \
            const int col = (((c & 15) ^ (row & 15)) << 3);                   \
            GLOAD_LDS16(e16 + ((size_t)((kcc) * 128 + row)) * Dn + (hh) * 128 + col, \
                        (dst) + ((r * 512 + (wid << 6)) << 3));               \
        }                                                                     \
    }

// plain accumulate phase (d-half via afArr, B from bbuf)
#define COMPUTE_ACC(bbuf, afArr)                                              \
    {                                                                         \
        __builtin_amdgcn_s_setprio(1);                                        \
        _Pragma("unroll")                                                     \
        for (int ks = 0; ks < 4; ++ks)                                        \
            _Pragma("unroll")                                                 \
            for (int j = 0; j < 8; ++j) {                                     \
                const f16x8 bf = *(const f16x8*)(                             \
                    &(bbuf)[((j << 4) + l15) * 128 +                          \
                            ((((ks << 2) | quad) ^ l15) << 3)]);              \
                _Pragma("unroll")                                             \
                for (int i = 0; i < 2; ++i)                                   \
                    acc[i][j] = __builtin_amdgcn_mfma_f32_16x16x32_f16(       \
                        afArr[ks * 2 + i], bf, acc[i][j], 0, 0, 0);           \
            }                                                                 \
        __builtin_amdgcn_s_setprio(0);                                        \
    }

__global__ __launch_bounds__(512, 2) void gemm_argmax(
    const float* __restrict__ x, const ushort_t* __restrict__ e16,
    const float* __restrict__ bias_g, int* __restrict__ codes_i,
    float* __restrict__ codes_f, int* __restrict__ list,
    int* __restrict__ counter)
{
    __shared__ __align__(16) ushort_t BsS[2][128 * 128]; // 2 x 32 KB
    __shared__ __align__(16) float    biasLds[2048];     // 8 KB

    const int bid = blockIdx.x;          // 256 blocks: one 256-t tile each
    const int b   = bid >> 4;
    const int tt  = bid & 15;
    const int t0  = tt << 8;

    const int tid  = threadIdx.x;
    const int lane = tid & 63;
    const int wid  = tid >> 6;           // 8 waves, each owns 32 t-rows
    const int l15  = lane & 15;
    const int quad = lane >> 4;
    const int wm   = wid;                // t-block of 32 rows

    const size_t bTt0 = (size_t)b * Tn + t0;

    // ---- prologue: bias -> LDS; A -> registers directly from x ----
    GLOAD_LDS16(bias_g + (tid << 2), biasLds + (wid << 8));   // 1 outstanding

    // persistent A fragments: 2 halves x (4 ks x 2 i) = 16 f16x8 = 64 VGPR
    f16x8 af0[8], af1[8];
    {
        const float* xb = x + (size_t)b * Dn * Tn;   // [D][T]
        #pragma unroll
        for (int ks = 0; ks < 4; ++ks)
            #pragma unroll
            for (int i = 0; i < 2; ++i) {
                const int t = t0 + (wm << 5) + (i << 4) + l15;
                const float* c0 = xb + ((size_t)(ks * 32 + quad * 8)) * Tn + t;
                const float* c1 = c0 + (size_t)128 * Tn;
                f16x8 v0, v1;
                #pragma unroll
                for (int e = 0; e < 8; ++e) {
                    v0[e] = (_Float16)c0[(size_t)e * Tn];
                    v1[e] = (_Float16)c1[(size_t)e * Tn];
                }
                af0[ks * 2 + i] = v0;
                af1[ks * 2 + i] = v1;
            }
    }

    // accumulators: 2 i x 8 j = 64 regs
    f32x4 acc[2][8];
    // top-2 state per (i,r): 24 regs
    float S1[2][4], S2[2][4];
    int   K1[2][4];
    #pragma unroll
    for (int i = 0; i < 2; ++i)
        #pragma unroll
        for (int r = 0; r < 4; ++r) { S1[i][r] = -INFINITY; S2[i][r] = -INFINITY; K1[i][r] = 0; }
    #pragma unroll
    for (int i = 0; i < 2; ++i)
        #pragma unroll
        for (int j = 0; j < 8; ++j)
            acc[i][j] = (f32x4){-INFINITY, -INFINITY, -INFINITY, -INFINITY};

    asm volatile("s_waitcnt vmcnt(0)" ::: "memory");   // bias + A loads landed
    BARRIER_PIN();                                     // biasLds visible
    STAGE_B(&BsS[0][0], 0, 0);                         // 4
    STAGE_B(&BsS[1][0], 0, 1);                         // 4 -> 8 outstanding

    #pragma unroll 1
    for (int kc = 0; kc < 16; ++kc) {
        // ---- phase h0 (d 0..127, Bs0): drain prev-kc acc + C=-bias re-init --
        asm volatile("s_waitcnt vmcnt(4)" ::: "memory");
        BARRIER_PIN();
        {
            float bj[8];
            #pragma unroll
            for (int j = 0; j < 8; ++j)
                bj[j] = biasLds[(kc << 7) + (j << 4) + l15];
            const int kdrb = ((kc - 1) << 7) + l15;   // k of drained values
            __builtin_amdgcn_s_setprio(1);
            #pragma unroll
            for (int j = 0; j < 8; ++j) {
                const f16x8 bf0 = *(const f16x8*)(
                    &BsS[0][((j << 4) + l15) * 128 + ((quad ^ l15) << 3)]);
                const float nb = -bj[j];
                const f32x4 cin = {nb, nb, nb, nb};
                const int kdr = kdrb + (j << 4);
                #pragma unroll
                for (int i = 0; i < 2; ++i) {
                    // drain old acc[i][j]: med3 top-2 insert (kc==0: -INF, harmless)
                    #pragma unroll
                    for (int r = 0; r < 4; ++r) {
                        const float s = acc[i][j][r];
                        S2[i][r] = __builtin_amdgcn_fmed3f(s, S1[i][r], S2[i][r]);
                        const bool gt = s > S1[i][r];
                        K1[i][r] = gt ? kdr : K1[i][r];
                        S1[i][r] = fmaxf(S1[i][r], s);
                    }
                    acc[i][j] = __builtin_amdgcn_mfma_f32_16x16x32_f16(
                        af0[i], bf0, cin, 0, 0, 0);
                }
            }
            #pragma unroll
            for (int ks = 1; ks < 4; ++ks)
                #pragma unroll
                for (int j = 0; j < 8; ++j) {
                    const f16x8 bf = *(const f16x8*)(
                        &BsS[0][((j << 4) + l15) * 128 +
                                ((((ks << 2) | quad) ^ l15) << 3)]);
                    #pragma unroll
                    for (int i = 0; i < 2; ++i)
                        acc[i][j] = __builtin_amdgcn_mfma_f32_16x16x32_f16(
                            af0[ks * 2 + i], bf, acc[i][j], 0, 0, 0);
                }
            __builtin_amdgcn_s_setprio(0);
        }
        BARRIER_PIN();                       // WAR: Bs0 readers done
        if (kc < 15) STAGE_B(&BsS[0][0], kc + 1, 0);

        // ---- phase h1 (d 128..255, Bs1): plain accumulate ----
        if (kc < 15) { asm volatile("s_waitcnt vmcnt(4)" ::: "memory"); }
        else         { asm volatile("s_waitcnt vmcnt(0)" ::: "memory"); }
        BARRIER_PIN();
        COMPUTE_ACC((&BsS[1][0]), af1);
        BARRIER_PIN();                       // WAR: Bs1 readers done
        if (kc < 15) STAGE_B(&BsS[1][0], kc + 1, 1);
    }

    __builtin_amdgcn_sched_barrier(0);

    // ---- final drain of kc=15 acc ----
    {
        const int kfb = (15 << 7) + l15;
        #pragma unroll
        for (int j = 0; j < 8; ++j) {
            const int kf = kfb + (j << 4);
            #pragma unroll
            for (int i = 0; i < 2; ++i)
                #pragma unroll
                for (int r = 0; r < 4; ++r) {
                    const float s = acc[i][j][r];
                    S2[i][r] = __builtin_amdgcn_fmed3f(s, S1[i][r], S2[i][r]);
                    const bool gt = s > S1[i][r];
                    K1[i][r] = gt ? kf : K1[i][r];
                    S1[i][r] = fmaxf(S1[i][r], s);
                }
        }
    }

    // ---- butterfly across the 16 k-lanes (tie-break: lowest k) ----
    #pragma unroll
    for (int m = 1; m <= 8; m <<= 1) {
        #pragma unroll
        for (int i = 0; i < 2; ++i)
            #pragma unroll
            for (int r = 0; r < 4; ++r) {
                const float os1 = __shfl_xor(S1[i][r], m);
                const float os2 = __shfl_xor(S2[i][r], m);
                const int   ok1 = __shfl_xor(K1[i][r], m);
                const bool take = (os1 > S1[i][r]) || (os1 == S1[i][r] && ok1 < K1[i][r]);
                const float ns2 = take ? fmaxf(S1[i][r], os2) : fmaxf(S2[i][r], os1);
                if (take) { S1[i][r] = os1; K1[i][r] = ok1; }
                S2[i][r] = ns2;
            }
    }

    if (l15 == 0) {
        #pragma unroll
        for (int i = 0; i < 2; ++i)
            #pragma unroll
            for (int r = 0; r < 4; ++r) {
                const int row = (wm << 5) + (i << 4) + (quad << 2) + r;
                const size_t p = bTt0 + row;
                const int wk = K1[i][r];
                codes_i[p] = wk;
                codes_f[p] = (float)wk;
                if (S1[i][r] - S2[i][r] < TAU) {
                    const int idx = atomicAdd(counter, 1);
                    list[idx] = (int)p;
                }
            }
    }
}

// ---------------------------------------------------------------------------
// Kernel 5: exact fp32 rescore (unchanged)
// ---------------------------------------------------------------------------
__global__ __launch_bounds__(256) void rescue_kernel(
    const float* __restrict__ x, const float4* __restrict__ embT4,
    const float* __restrict__ bias, const int* __restrict__ list,
    const int* __restrict__ counter, int* __restrict__ codes_i,
    float* __restrict__ codes_f)
{
    __shared__ float xv[RP][256];
    __shared__ int plist[RP];
    __shared__ float rs[RP][4];
    __shared__ int   rk[RP][4];
    const int tid = threadIdx.x, lane = tid & 63, wid = tid >> 6;
    const int count = *counter;
    for (int base = blockIdx.x * RP; base < count; base += gridDim.x * RP) {
        const int npts = min(RP, count - base);
        __syncthreads();
        if (tid < npts) plist[tid] = list[base + tid];
        __syncthreads();
        for (int pi = 0; pi < npts; ++pi) {
            const int p = plist[pi];
            xv[pi][tid] = x[((size_t)((p >> 12) * Dn + tid)) * Tn + (p & 4095)];
        }
        for (int pi = npts; pi < RP; ++pi) xv[pi][tid] = 0.f;
        __syncthreads();

        float acc[8][RP];
        #pragma unroll
        for (int s = 0; s < 8; ++s)
            #pragma unroll
            for (int pi = 0; pi < RP; ++pi) acc[s][pi] = 0.f;

        for (int dc = 0; dc < 64; ++dc) {
            float4 ev[8];
            #pragma unroll
            for (int s = 0; s < 8; ++s)
                ev[s] = embT4[(size_t)dc * Kn + tid + (s << 8)];
            #pragma unroll
            for (int pi = 0; pi < RP; ++pi) {
                const float4 xw = *(const float4*)&xv[pi][dc << 2];
                #pragma unroll
                for (int s = 0; s < 8; ++s)
                    acc[s][pi] += ev[s].x * xw.x + ev[s].y * xw.y
                                + ev[s].z * xw.z + ev[s].w * xw.w;
            }
        }

        float bs[RP]; int bk[RP];
        #pragma unroll
        for (int pi = 0; pi < RP; ++pi) { bs[pi] = -INFINITY; bk[pi] = 0; }
        #pragma unroll
        for (int s = 0; s < 8; ++s) {
            const int kk = tid + (s << 8);
            const float bv = bias[kk];
            #pragma unroll
            for (int pi = 0; pi < RP; ++pi) {
                const float sc = acc[s][pi] - bv;
                if (sc > bs[pi]) { bs[pi] = sc; bk[pi] = kk; }
            }
        }
        #pragma unroll
        for (int off = 1; off < 64; off <<= 1) {
            #pragma unroll
            for (int pi = 0; pi < RP; ++pi) {
                const float os = __shfl_xor(bs[pi], off);
                const int   ok = __shfl_xor(bk[pi], off);
                if (os > bs[pi] || (os == bs[pi] && ok < bk[pi])) { bs[pi] = os; bk[pi] = ok; }
            }
        }
        if (lane == 0) {
            #pragma unroll
            for (int pi = 0; pi < RP; ++pi) { rs[pi][wid] = bs[pi]; rk[pi][wid] = bk[pi]; }
        }
        __syncthreads();
        if (tid < npts) {
            float fs = rs[tid][0]; int fk = rk[tid][0];
            #pragma unroll
            for (int w = 1; w < 4; ++w) {
                if (rs[tid][w] > fs || (rs[tid][w] == fs && rk[tid][w] < fk)) {
                    fs = rs[tid][w]; fk = rk[tid][w];
                }
            }
            const int p = plist[tid];
            codes_i[p] = fk;
            codes_f[p] = (float)fk;
        }
    }
}

// ---------------------------------------------------------------------------
// Kernel 6: decode (unchanged)
// ---------------------------------------------------------------------------
__global__ __launch_bounds__(256) void decode_kernel(
    const float* __restrict__ emb, const int* __restrict__ codes,
    float* __restrict__ out)
{
    const int b = blockIdx.y;
    const int t = blockIdx.x * 256 + threadIdx.x;
    const int c = codes[(size_t)b * Tn + t];
    const float4* e4 = (const float4*)(emb + (size_t)c * Dn);
    float* ob = out + (size_t)b * Dn * Tn + t;
    #pragma unroll 4
    for (int d4 = 0; d4 < 64; ++d4) {
        const float4 v = e4[d4];
        ob[(size_t)(d4 * 4 + 0) * Tn] = v.x;
        ob[(size_t)(d4 * 4 + 1) * Tn] = v.y;
        ob[(size_t)(d4 * 4 + 2) * Tn] = v.z;
        ob[(size_t)(d4 * 4 + 3) * Tn] = v.w;
    }
}

// ---------------------------------------------------------------------------
extern "C" void kernel_launch(void* const* d_in, const int* in_sizes, int n_in,
                              void* d_out, int out_size, void* d_ws, size_t ws_size,
                              hipStream_t stream) {
    const float* x     = (const float*)d_in[0];   // [B, D, T]
    const float* es    = (const float*)d_in[1];   // [K, D]
    const float* usage = (const float*)d_in[2];   // [K]

    // ws layout (byte offsets, 16-aligned) — ~6 MiB
    char* ws = (char*)d_ws;
    float*    emb     = (float*)(ws + 0);                // 2 MiB
    float*    bias    = (float*)(ws + 2097152);          // 8 KB
    ushort_t* e16     = (ushort_t*)(ws + 2105344);       // 1 MiB
    float4*   embT4   = (float4*)(ws + 3153920);         // 2 MiB
    int*      codes_i = (int*)(ws + 5251072);            // 256 KB
    int*      list    = (int*)(ws + 5513216);            // 256 KB
    int*      counter = (int*)(ws + 5775360);            // 4 B

    float* codes_f = (float*)d_out;                      // [B*T]
    float* decoded = (float*)d_out + (size_t)Bn * Tn;    // [B*D*T], 64 MiB
    // (no xh buffer anymore: gemm reads x directly; decoded region untouched
    //  until decode_kernel)

    prep_kernel<<<Kn, 256, 0, stream>>>(es, usage, emb, e16, bias, embT4, counter);

    // 256 blocks (one per CU), each: 256 t x full K=2048, A in registers
    gemm_argmax<<<256, 512, 0, stream>>>(x, e16, bias, codes_i, codes_f,
                                         list, counter);

    rescue_kernel<<<1024, 256, 0, stream>>>(x, embT4, bias, list, counter, codes_i, codes_f);

    dim3 g6(Tn / 256, Bn);
    decode_kernel<<<g6, 256, 0, stream>>>(emb, codes_i, decoded);
}